// Round 11
// baseline (892.096 us; speedup 1.0000x reference)
//
#include <hip/hip_runtime.h>

#define POOL_SHIFT 2
#define GRID_DIM 64
#define NUM_CELLS 4096
#define NCH 64
#define BATCH 64
#define QCS 16                      // 16 channel-quads of 4 channels
#define SENTINEL ((int)0x80000000)  // maps to no real float (only NaN)
#define ABL_REPS 4                  // per-ablation reps (crosses 152us top-5 cutoff)

typedef float vf4 __attribute__((ext_vector_type(4)));

// ---- K0: batch row ranges (batch is sorted) ----
__global__ __launch_bounds__(256) void bounds_kernel(
    const int* __restrict__ batch, int* __restrict__ bstart, int n) {
    int p = blockIdx.x * blockDim.x + threadIdx.x;
    if (p >= n) return;
    int b = batch[p];
    if (p == 0) {
        for (int i = 0; i <= b; ++i) bstart[i] = 0;
    } else {
        int pb = batch[p - 1];
        for (int i = pb + 1; i <= b; ++i) bstart[i] = p;
    }
    if (p == n - 1) {
        for (int i = b + 1; i <= BATCH; ++i) bstart[i] = n;
    }
}

// order-preserving float->int map (finite floats; inputs have no NaN)
__device__ __forceinline__ int fmap(float f) {
    int i = __float_as_int(f);
    return i >= 0 ? i : (i ^ 0x7fffffff);
}
__device__ __forceinline__ float funmap(int m) {
    if (m == SENTINEL) return 0.0f;              // empty cell -> 0 (ref semantics)
    return __int_as_float(m >= 0 ? m : (m ^ 0x7fffffff));
}

__device__ __forceinline__ void accum(int* acc, int2 pp, vf4 v) {
    int c = ((pp.x >> POOL_SHIFT) << 6) | (pp.y >> POOL_SHIFT);
    atomicMax(&acc[0 * NUM_CELLS + c], fmap(v.x));
    atomicMax(&acc[1 * NUM_CELLS + c], fmap(v.y));
    atomicMax(&acc[2 * NUM_CELLS + c], fmap(v.z));
    atomicMax(&acc[3 * NUM_CELLS + c], fmap(v.w));
}

// plain (non-atomic) stores to the same addresses: DS pipe + conflicts,
// minus the RMW/atomic serialization. Values garbage; never flushed.
__device__ __forceinline__ void accum_write(int* acc, int2 pp, vf4 v) {
    int c = ((pp.x >> POOL_SHIFT) << 6) | (pp.y >> POOL_SHIFT);
    acc[0 * NUM_CELLS + c] = fmap(v.x);
    acc[1 * NUM_CELLS + c] = fmap(v.y);
    acc[2 * NUM_CELLS + c] = fmap(v.z);
    acc[3 * NUM_CELLS + c] = fmap(v.w);
}

// ---- K1: the CORRECT pool (round-7 structure, best verified: 409 us) ----
__global__ __launch_bounds__(256, 2) void pool_kernel(
    const float* __restrict__ x, const int* __restrict__ pos,
    const int* __restrict__ bstart, float* __restrict__ out) {
    __shared__ int acc[4 * NUM_CELLS];   // 64 KB, plane-major [j][cell]
    const int L   = (int)blockIdx.x;
    const int xcd = L & 7;
    const int qc  = (L >> 3) & 15;
    const int grp = L >> 7;
    const int b0  = grp * 8 + xcd;
    const int t   = threadIdx.x;

    const vf4* xq  = (const vf4*)x;
    const int2* pq = (const int2*)pos;

    for (int half = 0; half < 2; ++half) {
        const int b = b0 + 32 * half;
        for (int i = t; i < 4 * NUM_CELLS; i += 256) acc[i] = SENTINEL;
        __syncthreads();
        const int r0 = bstart[b], r1 = bstart[b + 1];
        int r = r0 + t;
        for (; r + 768 < r1; r += 1024) {
            int2 pp0 = pq[r];
            int2 pp1 = pq[r + 256];
            int2 pp2 = pq[r + 512];
            int2 pp3 = pq[r + 768];
            vf4 v0 = xq[(size_t)r * QCS + qc];
            vf4 v1 = xq[(size_t)(r + 256) * QCS + qc];
            vf4 v2 = xq[(size_t)(r + 512) * QCS + qc];
            vf4 v3 = xq[(size_t)(r + 768) * QCS + qc];
            accum(acc, pp0, v0);
            accum(acc, pp1, v1);
            accum(acc, pp2, v2);
            accum(acc, pp3, v3);
        }
        for (; r < r1; r += 256) {
            int2 pp = pq[r];
            vf4 v = xq[(size_t)r * QCS + qc];
            accum(acc, pp, v);
        }
        __syncthreads();
        const size_t obase = (size_t)b * NUM_CELLS * NCH + (size_t)qc * 4;
        for (int c = t; c < NUM_CELLS; c += 256) {
            vf4 o;
            o.x = funmap(acc[0 * NUM_CELLS + c]);
            o.y = funmap(acc[1 * NUM_CELLS + c]);
            o.z = funmap(acc[2 * NUM_CELLS + c]);
            o.w = funmap(acc[3 * NUM_CELLS + c]);
            *(vf4*)&out[obase + (size_t)c * NCH] = o;
        }
        __syncthreads();
    }
}

// ---- ABLATION A: no x loads (constant v). pos + LDS atomics + loop kept.
// Never writes out. dummy-sink read of acc prevents LDS-store DCE.
__global__ __launch_bounds__(256, 2) void pool_ablA_kernel(
    const int* __restrict__ pos, const int* __restrict__ bstart,
    int* __restrict__ sink) {
    __shared__ int acc[4 * NUM_CELLS];
    const int L   = (int)blockIdx.x;
    const int xcd = L & 7;
    const int qc  = (L >> 3) & 15;   (void)qc;
    const int grp = L >> 7;
    const int b0  = grp * 8 + xcd;
    const int t   = threadIdx.x;
    const int2* pq = (const int2*)pos;
    const vf4 vc = (vf4)(1.0f);

    for (int rep = 0; rep < ABL_REPS; ++rep) {
        const int2* pqr = pq;
        const int* bsp = bstart;
        asm volatile("" : "+v"(pqr), "+v"(bsp));
        for (int half = 0; half < 2; ++half) {
            const int b = b0 + 32 * half;
            for (int i = t; i < 4 * NUM_CELLS; i += 256) acc[i] = SENTINEL;
            __syncthreads();
            const int r0 = bsp[b], r1 = bsp[b + 1];
            int r = r0 + t;
            for (; r + 768 < r1; r += 1024) {
                int2 pp0 = pqr[r];
                int2 pp1 = pqr[r + 256];
                int2 pp2 = pqr[r + 512];
                int2 pp3 = pqr[r + 768];
                accum(acc, pp0, vc);
                accum(acc, pp1, vc);
                accum(acc, pp2, vc);
                accum(acc, pp3, vc);
            }
            for (; r < r1; r += 256) accum(acc, pqr[r], vc);
            __syncthreads();
        }
    }
    // liveness sink (tiny, per-block)
    if (t == 0) sink[L] = acc[0] ^ acc[4096] ^ acc[8192] ^ acc[12288];
}

// ---- ABLATION B: x loads kept, atomicMax -> plain ds_write.
// Never writes out. Sink keeps LDS stores + x loads live.
__global__ __launch_bounds__(256, 2) void pool_ablB_kernel(
    const float* __restrict__ x, const int* __restrict__ pos,
    const int* __restrict__ bstart, int* __restrict__ sink) {
    __shared__ int acc[4 * NUM_CELLS];
    const int L   = (int)blockIdx.x;
    const int xcd = L & 7;
    const int qc  = (L >> 3) & 15;
    const int grp = L >> 7;
    const int b0  = grp * 8 + xcd;
    const int t   = threadIdx.x;
    const vf4* xq  = (const vf4*)x;
    const int2* pq = (const int2*)pos;

    for (int rep = 0; rep < ABL_REPS; ++rep) {
        const vf4* xqr = xq;
        const int2* pqr = pq;
        const int* bsp = bstart;
        asm volatile("" : "+v"(xqr), "+v"(pqr), "+v"(bsp));
        for (int half = 0; half < 2; ++half) {
            const int b = b0 + 32 * half;
            for (int i = t; i < 4 * NUM_CELLS; i += 256) acc[i] = SENTINEL;
            __syncthreads();
            const int r0 = bsp[b], r1 = bsp[b + 1];
            int r = r0 + t;
            for (; r + 768 < r1; r += 1024) {
                int2 pp0 = pqr[r];
                int2 pp1 = pqr[r + 256];
                int2 pp2 = pqr[r + 512];
                int2 pp3 = pqr[r + 768];
                vf4 v0 = xqr[(size_t)r * QCS + qc];
                vf4 v1 = xqr[(size_t)(r + 256) * QCS + qc];
                vf4 v2 = xqr[(size_t)(r + 512) * QCS + qc];
                vf4 v3 = xqr[(size_t)(r + 768) * QCS + qc];
                accum_write(acc, pp0, v0);
                accum_write(acc, pp1, v1);
                accum_write(acc, pp2, v2);
                accum_write(acc, pp3, v3);
            }
            for (; r < r1; r += 256) {
                int2 pp = pqr[r];
                vf4 v = xqr[(size_t)r * QCS + qc];
                accum_write(acc, pp, v);
            }
            __syncthreads();
        }
    }
    if (t == 0) sink[512 + L] = acc[1] ^ acc[4097] ^ acc[8193] ^ acc[12289];
}

extern "C" void kernel_launch(void* const* d_in, const int* in_sizes, int n_in,
                              void* d_out, int out_size, void* d_ws, size_t ws_size,
                              hipStream_t stream) {
    const float* x   = (const float*)d_in[0];
    const int* pos   = (const int*)d_in[1];
    const int* batch = (const int*)d_in[2];
    float* out = (float*)d_out;
    int n = in_sizes[2];

    int* bstart = (int*)d_ws;            // BATCH + 1 ints
    int* sink   = bstart + 128;          // 1024 ints of probe sink

    bounds_kernel<<<(n + 255) / 256, 256, 0, stream>>>(batch, bstart, n);
    pool_kernel<<<512, 256, 0, stream>>>(x, pos, bstart, out);          // correct output
    pool_ablA_kernel<<<512, 256, 0, stream>>>(pos, bstart, sink);       // probe: DS path
    pool_ablB_kernel<<<512, 256, 0, stream>>>(x, pos, bstart, sink);    // probe: x path
}

// Round 12
// 416.818 us; speedup vs baseline: 2.1403x; 2.1403x over previous
//
#include <hip/hip_runtime.h>

#define POOL_SHIFT 2
#define GRID_DIM 64
#define NUM_CELLS 4096
#define NCH 64
#define BATCH 64
#define OCS 8                       // 8 channel-octets of 8 channels
#define SENTINEL ((int)0x80000000)  // maps to no real float (only NaN)

typedef float vf4 __attribute__((ext_vector_type(4)));

// ---- K0: batch row ranges (batch is sorted) ----
__global__ __launch_bounds__(256) void bounds_kernel(
    const int* __restrict__ batch, int* __restrict__ bstart, int n) {
    int p = blockIdx.x * blockDim.x + threadIdx.x;
    if (p >= n) return;
    int b = batch[p];
    if (p == 0) {
        for (int i = 0; i <= b; ++i) bstart[i] = 0;
    } else {
        int pb = batch[p - 1];
        for (int i = pb + 1; i <= b; ++i) bstart[i] = p;
    }
    if (p == n - 1) {
        for (int i = b + 1; i <= BATCH; ++i) bstart[i] = n;
    }
}

// order-preserving float->int map (finite floats; inputs have no NaN)
__device__ __forceinline__ int fmap(float f) {
    int i = __float_as_int(f);
    return i >= 0 ? i : (i ^ 0x7fffffff);
}
__device__ __forceinline__ float funmap(int m) {
    if (m == SENTINEL) return 0.0f;              // empty cell -> 0 (ref semantics)
    return __int_as_float(m >= 0 ? m : (m ^ 0x7fffffff));
}

// plane j of cell c lives at acc[(j<<12) + (c ^ (j<<2))]: one lane's 8
// sequential atomics hit 8 distinct banks (XOR 0,4,...,28) instead of 1.
__device__ __forceinline__ void accum8(int* acc, int2 pp, vf4 a, vf4 b2) {
    int c = ((pp.x >> POOL_SHIFT) << 6) | (pp.y >> POOL_SHIFT);
    atomicMax(&acc[0 * NUM_CELLS + (c ^ 0)],  fmap(a.x));
    atomicMax(&acc[1 * NUM_CELLS + (c ^ 4)],  fmap(a.y));
    atomicMax(&acc[2 * NUM_CELLS + (c ^ 8)],  fmap(a.z));
    atomicMax(&acc[3 * NUM_CELLS + (c ^ 12)], fmap(a.w));
    atomicMax(&acc[4 * NUM_CELLS + (c ^ 16)], fmap(b2.x));
    atomicMax(&acc[5 * NUM_CELLS + (c ^ 20)], fmap(b2.y));
    atomicMax(&acc[6 * NUM_CELLS + (c ^ 24)], fmap(b2.z));
    atomicMax(&acc[7 * NUM_CELLS + (c ^ 28)], fmap(b2.w));
}

// ---- K1: one WG per (batch, channel-OCTET) ----
// Round-11 ablation: x-path = 107 of pool's ~122 us; cause is L1-miss
// line-request rate (16-B lane reads at stride 256 -> every lane a
// distinct, unshared 64-B line -> 16M L2 requests). Fix: 8-channel
// (32-B) slices. The two adjacent vf4 loads share one 64-B line, so the
// second is an L1 hit -> 8M line-requests at identical atomic count and
// identical HBM bytes. LDS acc = 8 planes * 4096 cells = 128 KB (dynamic),
// 1024 threads, 1 WG/CU. Grid: L = oc*64 + b -> XCD = b&7, so the octet
// pair (2k,2k+1) sharing each line is co-resident on one XCD in the same
// scheduling round (oc<4 first, oc>=4 second) -> L2 dedups HBM fetch
// (validated: round-9/11 FETCH ~= 1x of x).
__global__ __launch_bounds__(1024, 4) void pool_kernel(
    const float* __restrict__ x, const int* __restrict__ pos,
    const int* __restrict__ bstart, float* __restrict__ out) {
    extern __shared__ int acc[];         // 8 * NUM_CELLS ints = 128 KB
    const int L  = (int)blockIdx.x;
    const int b  = L & 63;
    const int oc = L >> 6;               // 0..7
    const int t  = threadIdx.x;          // 0..1023

    for (int i = t; i < 8 * NUM_CELLS; i += 1024) acc[i] = SENTINEL;
    __syncthreads();

    const int r0 = bstart[b], r1 = bstart[b + 1];
    const vf4* xq  = (const vf4*)x;      // row r, quad q -> xq[r*16 + q]
    const int2* pq = (const int2*)pos;
    const int q0 = oc * 2;               // first quad of this octet

    int r = r0 + t;
    // 4 independent row-iterations in flight per lane
    for (; r + 3072 < r1; r += 4096) {
        int2 pp0 = pq[r];
        int2 pp1 = pq[r + 1024];
        int2 pp2 = pq[r + 2048];
        int2 pp3 = pq[r + 3072];
        vf4 a0 = xq[(size_t)r * 16 + q0];
        vf4 b0 = xq[(size_t)r * 16 + q0 + 1];
        vf4 a1 = xq[(size_t)(r + 1024) * 16 + q0];
        vf4 b1 = xq[(size_t)(r + 1024) * 16 + q0 + 1];
        vf4 a2 = xq[(size_t)(r + 2048) * 16 + q0];
        vf4 b2 = xq[(size_t)(r + 2048) * 16 + q0 + 1];
        vf4 a3 = xq[(size_t)(r + 3072) * 16 + q0];
        vf4 b3 = xq[(size_t)(r + 3072) * 16 + q0 + 1];
        accum8(acc, pp0, a0, b0);
        accum8(acc, pp1, a1, b1);
        accum8(acc, pp2, a2, b2);
        accum8(acc, pp3, a3, b3);
    }
    for (; r < r1; r += 1024) {
        int2 pp = pq[r];
        vf4 a = xq[(size_t)r * 16 + q0];
        vf4 b2 = xq[(size_t)r * 16 + q0 + 1];
        accum8(acc, pp, a, b2);
    }
    __syncthreads();

    // flush: channels oc*8 .. oc*8+7 of every cell of batch b
    const size_t obase = (size_t)b * NUM_CELLS * NCH + (size_t)oc * 8;
    for (int c = t; c < NUM_CELLS; c += 1024) {
        vf4 o0, o1;
        o0.x = funmap(acc[0 * NUM_CELLS + (c ^ 0)]);
        o0.y = funmap(acc[1 * NUM_CELLS + (c ^ 4)]);
        o0.z = funmap(acc[2 * NUM_CELLS + (c ^ 8)]);
        o0.w = funmap(acc[3 * NUM_CELLS + (c ^ 12)]);
        o1.x = funmap(acc[4 * NUM_CELLS + (c ^ 16)]);
        o1.y = funmap(acc[5 * NUM_CELLS + (c ^ 20)]);
        o1.z = funmap(acc[6 * NUM_CELLS + (c ^ 24)]);
        o1.w = funmap(acc[7 * NUM_CELLS + (c ^ 28)]);
        *(vf4*)&out[obase + (size_t)c * NCH]     = o0;
        *(vf4*)&out[obase + (size_t)c * NCH + 4] = o1;
    }
}

extern "C" void kernel_launch(void* const* d_in, const int* in_sizes, int n_in,
                              void* d_out, int out_size, void* d_ws, size_t ws_size,
                              hipStream_t stream) {
    const float* x   = (const float*)d_in[0];
    const int* pos   = (const int*)d_in[1];
    const int* batch = (const int*)d_in[2];
    float* out = (float*)d_out;
    int n = in_sizes[2];

    int* bstart = (int*)d_ws;           // BATCH + 1 ints

    bounds_kernel<<<(n + 255) / 256, 256, 0, stream>>>(batch, bstart, n);
    pool_kernel<<<BATCH * OCS, 1024, 8 * NUM_CELLS * sizeof(int), stream>>>(
        x, pos, bstart, out);
}

// Round 13
// 410.184 us; speedup vs baseline: 2.1749x; 1.0162x over previous
//
#include <hip/hip_runtime.h>

#define POOL_SHIFT 2
#define GRID_DIM 64
#define NUM_CELLS 4096
#define NCH 64
#define BATCH 64
#define QCS 16                      // 16 channel-quads of 4 channels
#define SENTINEL ((int)0x80000000)  // maps to no real float (only NaN)

typedef float vf4 __attribute__((ext_vector_type(4)));

// ---- K0: batch row ranges (batch is sorted) ----
__global__ __launch_bounds__(256) void bounds_kernel(
    const int* __restrict__ batch, int* __restrict__ bstart, int n) {
    int p = blockIdx.x * blockDim.x + threadIdx.x;
    if (p >= n) return;
    int b = batch[p];
    if (p == 0) {
        for (int i = 0; i <= b; ++i) bstart[i] = 0;
    } else {
        int pb = batch[p - 1];
        for (int i = pb + 1; i <= b; ++i) bstart[i] = p;
    }
    if (p == n - 1) {
        for (int i = b + 1; i <= BATCH; ++i) bstart[i] = n;
    }
}

// order-preserving float->int map (finite floats; inputs have no NaN)
__device__ __forceinline__ int fmap(float f) {
    int i = __float_as_int(f);
    return i >= 0 ? i : (i ^ 0x7fffffff);
}
__device__ __forceinline__ float funmap(int m) {
    if (m == SENTINEL) return 0.0f;              // empty cell -> 0 (ref semantics)
    return __int_as_float(m >= 0 ? m : (m ^ 0x7fffffff));
}

__device__ __forceinline__ void accum(int* acc, int2 pp, vf4 v) {
    int c = ((pp.x >> POOL_SHIFT) << 6) | (pp.y >> POOL_SHIFT);
    // plane-major acc[j][c]: bank = c & 31 -> ~2-way aliasing, free (m136)
    atomicMax(&acc[0 * NUM_CELLS + c], fmap(v.x));
    atomicMax(&acc[1 * NUM_CELLS + c], fmap(v.y));
    atomicMax(&acc[2 * NUM_CELLS + c], fmap(v.z));
    atomicMax(&acc[3 * NUM_CELLS + c], fmap(v.w));
}

// ---- K1: persistent (batch-pair, channel-quad) workgroups ----
// BEST-MEASURED VARIANT (round 7: 408.9 us). Session conclusion: the
// x-read path (~107 us, measured by ablation) is pinned by a per-CU
// line-request cost (~4 cyc per distinct 64-B line; 64 lines per
// wave-load at the inherent 256-B row stride -> ~2.4 TB/s cap).
// Wider slices / dup-reads / transposes / global atomics all cost >=
// what they save (slice-width x dup-count is conserved); LDS cannot
// hold the full-channel accumulator (1 MB > 160 KB) that contiguous
// streaming would need. Occupancy/MLP/bank-swizzle variations measured
// as exact ties (rounds 8, 10, 12). This is the structural floor.
__global__ __launch_bounds__(256, 2) void pool_kernel(
    const float* __restrict__ x, const int* __restrict__ pos,
    const int* __restrict__ bstart, float* __restrict__ out) {
    __shared__ int acc[4 * NUM_CELLS];   // 64 KB, plane-major [j][cell]
    const int L   = (int)blockIdx.x;
    const int xcd = L & 7;
    const int qc  = (L >> 3) & 15;
    const int grp = L >> 7;              // 0..3
    const int b0  = grp * 8 + xcd;       // 0..31
    const int t   = threadIdx.x;

    const vf4* xq  = (const vf4*)x;      // row r, quad qc -> xq[r*16 + qc]
    const int2* pq = (const int2*)pos;

    for (int half = 0; half < 2; ++half) {
        const int b = b0 + 32 * half;

        for (int i = t; i < 4 * NUM_CELLS; i += 256) acc[i] = SENTINEL;
        __syncthreads();

        const int r0 = bstart[b], r1 = bstart[b + 1];

        int r = r0 + t;
        // 4 independent row-loads in flight per lane
        for (; r + 768 < r1; r += 1024) {
            int2 pp0 = pq[r];
            int2 pp1 = pq[r + 256];
            int2 pp2 = pq[r + 512];
            int2 pp3 = pq[r + 768];
            vf4 v0 = xq[(size_t)r * QCS + qc];
            vf4 v1 = xq[(size_t)(r + 256) * QCS + qc];
            vf4 v2 = xq[(size_t)(r + 512) * QCS + qc];
            vf4 v3 = xq[(size_t)(r + 768) * QCS + qc];
            accum(acc, pp0, v0);
            accum(acc, pp1, v1);
            accum(acc, pp2, v2);
            accum(acc, pp3, v3);
        }
        for (; r < r1; r += 256) {
            int2 pp = pq[r];
            vf4 v = xq[(size_t)r * QCS + qc];
            accum(acc, pp, v);
        }
        __syncthreads();

        // flush: channels qc*4 .. qc*4+3 of every cell of batch b
        const size_t obase = (size_t)b * NUM_CELLS * NCH + (size_t)qc * 4;
        for (int c = t; c < NUM_CELLS; c += 256) {
            vf4 o;
            o.x = funmap(acc[0 * NUM_CELLS + c]);
            o.y = funmap(acc[1 * NUM_CELLS + c]);
            o.z = funmap(acc[2 * NUM_CELLS + c]);
            o.w = funmap(acc[3 * NUM_CELLS + c]);
            *(vf4*)&out[obase + (size_t)c * NCH] = o;  // L2 merges quad-siblings
        }
        __syncthreads();   // flush reads acc before next half re-inits
    }
}

extern "C" void kernel_launch(void* const* d_in, const int* in_sizes, int n_in,
                              void* d_out, int out_size, void* d_ws, size_t ws_size,
                              hipStream_t stream) {
    const float* x   = (const float*)d_in[0];
    const int* pos   = (const int*)d_in[1];
    const int* batch = (const int*)d_in[2];
    float* out = (float*)d_out;
    int n = in_sizes[2];

    int* bstart = (int*)d_ws;           // BATCH + 1 ints

    bounds_kernel<<<(n + 255) / 256, 256, 0, stream>>>(batch, bstart, n);
    pool_kernel<<<512, 256, 0, stream>>>(x, pos, bstart, out);
}